// Round 1
// baseline (12121.623 us; speedup 1.0000x reference)
//
#include <hip/hip_runtime.h>
#include <hip/hip_cooperative_groups.h>

namespace cg = cooperative_groups;

// Problem constants
#define TT 256
#define BB 256
#define EE 512
#define HH 1024
#define G4 4096
#define KTOT 1536
#define BK 128
#define APAD 8

typedef __attribute__((ext_vector_type(8))) short short8;
typedef __attribute__((ext_vector_type(4))) short short4v;
typedef __attribute__((ext_vector_type(4))) float f32x4;

__device__ __forceinline__ short f2bf(float f) {
    unsigned u; __builtin_memcpy(&u, &f, 4);
    unsigned r = (u + 0x7FFFu + ((u >> 16) & 1u)) >> 16;   // RNE
    return (short)(unsigned short)r;
}
__device__ __forceinline__ float bf2f(short s) {
    unsigned u = ((unsigned)(unsigned short)s) << 16;
    float f; __builtin_memcpy(&f, &u, 4);
    return f;
}
// sigmoid / tanh via v_exp_f32 + v_rcp_f32 (avoids libm tanhf's long chain)
__device__ __forceinline__ float sigf(float x) {
    return __builtin_amdgcn_rcpf(1.f + __expf(-x));
}
__device__ __forceinline__ float tanh_fast(float x) {
    return 2.f * sigf(x + x) - 1.f;   // 2*sigma(2x)-1; saturates correctly at +/-inf
}

// ---------------------------------------------------------------------------
// Prep: w_cat[r][0:1024]=w_hh[r], w_cat[r][1024:1536]=w_ih[r] (bf16);
//       bias[r] = b_ih[r] + b_hh[r]
// ---------------------------------------------------------------------------
__global__ __launch_bounds__(256) void prep_kernel(
    const float* __restrict__ w_ih, const float* __restrict__ w_hh,
    const float* __restrict__ b_ih, const float* __restrict__ b_hh,
    short* __restrict__ w_cat, float* __restrict__ bias)
{
    int r = blockIdx.x;
    int tid = threadIdx.x;
    for (int c = tid; c < KTOT; c += 256) {
        float v = (c < HH) ? w_hh[(size_t)r * HH + c]
                           : w_ih[(size_t)r * EE + (c - HH)];
        w_cat[(size_t)r * KTOT + c] = f2bf(v);
    }
    if (tid == 0) bias[r] = b_ih[r] + b_hh[r];
}

// ---------------------------------------------------------------------------
// Gather + convert: x_bf[t][b][:] = bf16(emb[text[b][t]][:])
// ---------------------------------------------------------------------------
__global__ __launch_bounds__(256) void gather_kernel(
    const int* __restrict__ text, const float* __restrict__ emb,
    short* __restrict__ xbf)
{
    int row = blockIdx.x * 4 + (threadIdx.x >> 6);   // b*TT + t
    int b = row >> 8, t = row & 255;
    int lane = threadIdx.x & 63;
    int v = text[row];
    const float* src = emb + (size_t)v * EE + lane * 8;
    float4 f0 = *(const float4*)src;
    float4 f1 = *(const float4*)(src + 4);
    float fv[8];
    *(float4*)&fv[0] = f0; *(float4*)&fv[4] = f1;
    short8 s;
    #pragma unroll
    for (int i = 0; i < 8; ++i) s[i] = f2bf(fv[i]);
    *(short8*)(xbf + ((size_t)t * BB + b) * EE + lane * 8) = s;
}

// ---------------------------------------------------------------------------
// Persistent LSTM: ALL 256 timesteps in one cooperative launch.
// Grid 256 blocks x 256 threads (4 waves), 1 block/CU.
// Block tile: 64 batch x 16 j x 4 gates (wave g = gate g) -- same traffic-
// optimal decomposition as before; grid.sync() replaces 256 kernel launches.
// c lives in registers for the whole sequence (each thread owns 4 cells).
// ---------------------------------------------------------------------------
__global__ __launch_bounds__(256) void lstm_seq(
    const short* __restrict__ w_cat,   // [4096][1536] bf16
    const float* __restrict__ bias,    // [4096]
    const short* __restrict__ xbf,     // [T][B][E] bf16
    short*       __restrict__ hbuf0,   // [B][H] bf16 (h_in at even t)
    short*       __restrict__ hbuf1)   // [B][H] bf16 (h_out at even t)
{
    cg::grid_group grid = cg::this_grid();

    __shared__ short At[2][64][BK + APAD];   // 34816 B
    __shared__ float Gt[4][64][17];          // 17408 B

    const int tid  = threadIdx.x;
    const int wv   = tid >> 6;               // gate 0..3 (i,f,g,o)
    const int lane = tid & 63;
    const int n    = lane & 15;
    const int q    = lane >> 4;

    // XCD-aware swizzle (bid % 8 = XCD, round-robin dispatch)
    const int bid = blockIdx.x;
    const int xcd = bid & 7, sub = bid >> 3;
    const int j0  = (xcd * 8 + (sub & 7)) * 16;   // 64 j-tiles
    const int b0  = (sub >> 3) * 64;              // 4 batch tiles

    const short* wrow = w_cat + (size_t)(wv * HH + j0 + n) * KTOT;

    // A staging: thread -> (row ar, cols ac..ac+31)
    const int ar = tid >> 2;
    const int ac = (tid & 3) * 32;
    const int ab = b0 + ar;
    const short* hrow0 = hbuf0 + (size_t)ab * HH;        // h_in at even t
    const short* hrow1 = hbuf1 + (size_t)ab * HH;        // h_in at odd t
    const short* xrow  = xbf + (size_t)ab * EE - HH;     // indexed by k0>=HH; +=B*E per t

    // Elementwise mapping (fixed across t): thread owns (batch eb, j jb..jb+3)
    const int m   = tid >> 2;
    const int n4  = (tid & 3) * 4;
    const int jb  = j0 + n4;
    const int eb  = b0 + m;
    float bi0[4], bf1[4], bg2[4], bo3[4];
    #pragma unroll
    for (int u = 0; u < 4; ++u) {
        bi0[u] = bias[jb + u];
        bf1[u] = bias[HH + jb + u];
        bg2[u] = bias[2 * HH + jb + u];
        bo3[u] = bias[3 * HH + jb + u];
    }
    float creg[4] = {0.f, 0.f, 0.f, 0.f};   // cell state, register-resident
    short* hout_even = hbuf1 + (size_t)eb * HH + jb;
    short* hout_odd  = hbuf0 + (size_t)eb * HH + jb;

    for (int t = 0; t < TT; ++t) {
        const short* hrow  = (t & 1) ? hrow1 : hrow0;
        const int kstart   = (t == 0) ? HH : 0;   // h == 0 at t=0: skip h chunks
        const int niter    = (KTOT - kstart) >> 7;

        f32x4 acc[4];
        #pragma unroll
        for (int i = 0; i < 4; ++i) acc[i] = (f32x4){0.f, 0.f, 0.f, 0.f};

        // Prologue: stage first chunk into buffer 0
        {
            const short* s = ((kstart < HH) ? hrow : xrow) + kstart + ac;
            *(short8*)&At[0][ar][ac]      = *(const short8*)(s);
            *(short8*)&At[0][ar][ac + 8]  = *(const short8*)(s + 8);
            *(short8*)&At[0][ar][ac + 16] = *(const short8*)(s + 16);
            *(short8*)&At[0][ar][ac + 24] = *(const short8*)(s + 24);
        }
        __syncthreads();

        for (int i = 0; i < niter; ++i) {
            const int k0  = kstart + (i << 7);
            const int cur = i & 1;
            const bool more = (i + 1 < niter);
            short8 r0, r1, r2, r3;
            if (more) {   // prefetch next chunk (global) before MFMAs
                const int kn = k0 + BK;
                const short* s = ((kn < HH) ? hrow : xrow) + kn + ac;
                r0 = *(const short8*)(s);
                r1 = *(const short8*)(s + 8);
                r2 = *(const short8*)(s + 16);
                r3 = *(const short8*)(s + 24);
            }
            #pragma unroll
            for (int ks = 0; ks < 4; ++ks) {
                short8 bfrag = *(const short8*)(wrow + k0 + ks * 32 + q * 8);
                #pragma unroll
                for (int mt = 0; mt < 4; ++mt) {
                    short8 afrag = *(const short8*)&At[cur][mt * 16 + n][ks * 32 + q * 8];
                    acc[mt] = __builtin_amdgcn_mfma_f32_16x16x32_bf16(afrag, bfrag, acc[mt], 0, 0, 0);
                }
            }
            if (more) {
                *(short8*)&At[cur ^ 1][ar][ac]      = r0;
                *(short8*)&At[cur ^ 1][ar][ac + 8]  = r1;
                *(short8*)&At[cur ^ 1][ar][ac + 16] = r2;
                *(short8*)&At[cur ^ 1][ar][ac + 24] = r3;
                __syncthreads();   // single barrier per iter (double-buffered)
            }
        }

        // Gate exchange through LDS
        #pragma unroll
        for (int mt = 0; mt < 4; ++mt)
            #pragma unroll
            for (int r = 0; r < 4; ++r)
                Gt[wv][mt * 16 + q * 4 + r][n] = acc[mt][r];
        __syncthreads();

        // Elementwise cell update (c in registers), packed 8-B h store
        short4v hv;
        #pragma unroll
        for (int u = 0; u < 4; ++u) {
            float ip = Gt[0][m][n4 + u] + bi0[u];
            float fp = Gt[1][m][n4 + u] + bf1[u];
            float gp = Gt[2][m][n4 + u] + bg2[u];
            float op = Gt[3][m][n4 + u] + bo3[u];
            float cn = sigf(fp) * creg[u] + sigf(ip) * tanh_fast(gp);
            creg[u]  = cn;
            hv[u]    = f2bf(sigf(op) * tanh_fast(cn));
        }
        *(short4v*)((t & 1) ? hout_odd : hout_even) = hv;

        xrow += (size_t)BB * EE;
        if (t + 1 < TT) grid.sync();   // h exchange across XCDs (device-scope fences)
    }
}

// ---------------------------------------------------------------------------
// FC head: out[b] = sigmoid(dot(h[b], fc_w) + fc_b)
// ---------------------------------------------------------------------------
__global__ __launch_bounds__(256) void fc_kernel(
    const short* __restrict__ hbuf, const float* __restrict__ fc_w,
    const float* __restrict__ fc_b, float* __restrict__ out)
{
    __shared__ float red[4];
    int b = blockIdx.x;
    int tid = threadIdx.x;
    float s = 0.f;
    for (int k = tid; k < HH; k += 256)
        s += bf2f(hbuf[(size_t)b * HH + k]) * fc_w[k];
    #pragma unroll
    for (int off = 32; off > 0; off >>= 1) s += __shfl_down(s, off);
    if ((tid & 63) == 0) red[tid >> 6] = s;
    __syncthreads();
    if (tid == 0) {
        float tot = red[0] + red[1] + red[2] + red[3] + fc_b[0];
        out[b] = 1.f / (1.f + __expf(-tot));
    }
}

// ---------------------------------------------------------------------------
// Workspace layout (bytes):
//   w_cat @ 0           : 4096*1536*2   = 12,582,912
//   bias  @ 12,582,912  : 4096*4        =     16,384
//   xbf   @ 12,599,296  : 256*256*512*2 = 67,108,864
//   hbuf0 @ 79,708,160  : 524,288
//   hbuf1 @ 80,232,448  : 524,288
//   (c region no longer used -- cell state lives in registers)
// ---------------------------------------------------------------------------
extern "C" void kernel_launch(void* const* d_in, const int* in_sizes, int n_in,
                              void* d_out, int out_size, void* d_ws, size_t ws_size,
                              hipStream_t stream) {
    const int*   text = (const int*)d_in[0];
    const float* emb  = (const float*)d_in[1];
    const float* w_ih = (const float*)d_in[2];
    const float* w_hh = (const float*)d_in[3];
    const float* b_ih = (const float*)d_in[4];
    const float* b_hh = (const float*)d_in[5];
    const float* fc_w = (const float*)d_in[6];
    const float* fc_b = (const float*)d_in[7];
    float* out = (float*)d_out;

    char* ws = (char*)d_ws;
    short* w_cat = (short*)(ws);
    float* bias  = (float*)(ws + 12582912);
    short* xbf   = (short*)(ws + 12599296);
    short* hbuf0 = (short*)(ws + 79708160);
    short* hbuf1 = (short*)(ws + 80232448);

    gather_kernel<<<dim3(BB * TT / 4), dim3(256), 0, stream>>>(text, emb, xbf);
    prep_kernel<<<dim3(G4), dim3(256), 0, stream>>>(w_ih, w_hh, b_ih, b_hh, w_cat, bias);

    // Persistent cooperative LSTM over all 256 timesteps
    const short* a0 = w_cat;
    const float* a1 = bias;
    const short* a2 = xbf;
    short*       a3 = hbuf0;
    short*       a4 = hbuf1;
    void* args[] = { (void*)&a0, (void*)&a1, (void*)&a2, (void*)&a3, (void*)&a4 };
    hipLaunchCooperativeKernel((const void*)lstm_seq, dim3(256), dim3(256),
                               args, 0, stream);

    // After t=255 (odd), final h is in hbuf0
    fc_kernel<<<dim3(BB), dim3(256), 0, stream>>>(hbuf0, fc_w, fc_b, out);
}

// Round 2
// 4092.648 us; speedup vs baseline: 2.9618x; 2.9618x over previous
//
#include <hip/hip_runtime.h>

// Problem constants
#define TT 256
#define BB 256
#define EE 512
#define HH 1024
#define G4 4096
#define KTOT 1536
#define BK 128
#define APAD 8
#define MB 32          // batch rows per block (8 groups of 32)
#define NBLK 512       // 64 j-tiles x 8 batch groups

typedef __attribute__((ext_vector_type(8))) short short8;
typedef __attribute__((ext_vector_type(4))) float f32x4;

__device__ __forceinline__ short f2bf(float f) {
    unsigned u; __builtin_memcpy(&u, &f, 4);
    unsigned r = (u + 0x7FFFu + ((u >> 16) & 1u)) >> 16;   // RNE
    return (short)(unsigned short)r;
}
__device__ __forceinline__ float bf2f(short s) {
    unsigned u = ((unsigned)(unsigned short)s) << 16;
    float f; __builtin_memcpy(&f, &u, 4);
    return f;
}
__device__ __forceinline__ float sigf(float x) {
    return __builtin_amdgcn_rcpf(1.f + __expf(-x));
}
__device__ __forceinline__ float tanh_fast(float x) {
    return 2.f * sigf(x + x) - 1.f;
}

// Device-coherent 16-B h load: two agent-scope relaxed 8-B atomic loads.
// These bypass (possibly stale) L1/L2 copies -> always fresh from L3.
__device__ __forceinline__ short8 load_h16(const short* p) {
    unsigned long long a = __hip_atomic_load((const unsigned long long*)p,
                                             __ATOMIC_RELAXED, __HIP_MEMORY_SCOPE_AGENT);
    unsigned long long b = __hip_atomic_load((const unsigned long long*)(p + 4),
                                             __ATOMIC_RELAXED, __HIP_MEMORY_SCOPE_AGENT);
    short8 v;
    __builtin_memcpy(&v, &a, 8);
    __builtin_memcpy((char*)&v + 8, &b, 8);
    return v;
}

// ---------------------------------------------------------------------------
// Prep: w_cat[r][0:1024]=w_hh[r], w_cat[r][1024:1536]=w_ih[r] (bf16);
//       bias[r] = b_ih[r] + b_hh[r]; block 0 also zeroes the barrier words
//       (atomic stores -> straight to L3, fresh every graph replay).
// ---------------------------------------------------------------------------
__global__ __launch_bounds__(256) void prep_kernel(
    const float* __restrict__ w_ih, const float* __restrict__ w_hh,
    const float* __restrict__ b_ih, const float* __restrict__ b_hh,
    short* __restrict__ w_cat, float* __restrict__ bias,
    unsigned* __restrict__ bar)
{
    int r = blockIdx.x;
    int tid = threadIdx.x;
    for (int c = tid; c < KTOT; c += 256) {
        float v = (c < HH) ? w_hh[(size_t)r * HH + c]
                           : w_ih[(size_t)r * EE + (c - HH)];
        w_cat[(size_t)r * KTOT + c] = f2bf(v);
    }
    if (tid == 0) bias[r] = b_ih[r] + b_hh[r];
    if (r == 0) {
        for (int i = tid; i < 512; i += 256)
            __hip_atomic_store(bar + i, 0u, __ATOMIC_RELAXED, __HIP_MEMORY_SCOPE_AGENT);
    }
}

// ---------------------------------------------------------------------------
// Gather + convert: x_bf[t][b][:] = bf16(emb[text[b][t]][:])
// ---------------------------------------------------------------------------
__global__ __launch_bounds__(256) void gather_kernel(
    const int* __restrict__ text, const float* __restrict__ emb,
    short* __restrict__ xbf)
{
    int row = blockIdx.x * 4 + (threadIdx.x >> 6);   // b*TT + t
    int b = row >> 8, t = row & 255;
    int lane = threadIdx.x & 63;
    int v = text[row];
    const float* src = emb + (size_t)v * EE + lane * 8;
    float4 f0 = *(const float4*)src;
    float4 f1 = *(const float4*)(src + 4);
    float fv[8];
    *(float4*)&fv[0] = f0; *(float4*)&fv[4] = f1;
    short8 s;
    #pragma unroll
    for (int i = 0; i < 8; ++i) s[i] = f2bf(fv[i]);
    *(short8*)(xbf + ((size_t)t * BB + b) * EE + lane * 8) = s;
}

// ---------------------------------------------------------------------------
// Persistent LSTM, 512 blocks x 256 threads (2 blocks/CU).
// Block = (batch group g: 32 rows) x (16 j) x (4 gates, wave = gate).
// 8 independent per-group barriers (64 blocks each) replace grid.sync():
//   store h (agent atomics, L2-bypass) -> syncthreads -> fetch_add count
//   -> compute x-part of NEXT step's gates -> spin on gen (s_sleep backoff).
// W and x stay normally cached (XCD-swizzled W slice resident in L2);
// no cache-maintenance instructions anywhere.
// ---------------------------------------------------------------------------
__global__ __launch_bounds__(256, 2) void lstm_seq(
    const short* __restrict__ w_cat,   // [4096][1536] bf16
    const float* __restrict__ bias,    // [4096]
    const short* __restrict__ xbf,     // [T][B][E] bf16
    short*       __restrict__ hbuf0,   // [B][H] bf16
    short*       __restrict__ hbuf1,   // [B][H] bf16
    unsigned*    __restrict__ bar)     // 8 groups x 64 u32 stride
{
    __shared__ short At[2][MB][BK + APAD];   // 2 x 32 x 136 bf16 = 17408 B
    __shared__ float Gt[4][MB][17];          // 8704 B   (total 26112 B)

    const int tid  = threadIdx.x;
    const int wv   = tid >> 6;               // gate 0..3 (i,f,g,o)
    const int lane = tid & 63;
    const int n    = lane & 15;
    const int q    = lane >> 4;

    const int bid = blockIdx.x;
    const int xcd = bid & 7, sub = bid >> 3;   // sub 0..63
    const int jt  = xcd * 8 + (sub & 7);       // 0..63 j-tile (XCD-swizzled)
    const int g   = sub >> 3;                  // 0..7 batch group
    const int j0  = jt * 16;
    const int b0  = g * MB;

    unsigned* cnt = bar + g * 64;
    unsigned* gen = bar + g * 64 + 16;

    const short* wrow = w_cat + (size_t)(wv * HH + j0 + n) * KTOT;

    // A staging: thread -> (row ar, cols ac..ac+15) of the 32x128 chunk
    const int ar = tid >> 3;                 // 0..31
    const int ac = (tid & 7) * 16;           // 0,16,...,112
    const int ab = b0 + ar;
    const short* hrow0 = hbuf0 + (size_t)ab * HH + ac;
    const short* hrow1 = hbuf1 + (size_t)ab * HH + ac;
    const short* xbase = xbf + (size_t)ab * EE + ac;

    // Elementwise mapping: thread owns (batch eb, j jb..jb+1)
    const int m  = tid >> 3;                 // 0..31
    const int n2 = (tid & 7) * 2;
    const int jb = j0 + n2;
    const int eb = b0 + m;
    float bi[2], bf_[2], bg[2], bo[2];
    #pragma unroll
    for (int u = 0; u < 2; ++u) {
        bi[u]  = bias[jb + u];
        bf_[u] = bias[HH + jb + u];
        bg[u]  = bias[2 * HH + jb + u];
        bo[u]  = bias[3 * HH + jb + u];
    }
    float creg[2] = {0.f, 0.f};
    unsigned* hout_e = (unsigned*)(hbuf1 + (size_t)eb * HH + jb);  // even t
    unsigned* hout_o = (unsigned*)(hbuf0 + (size_t)eb * HH + jb);  // odd t

    f32x4 acc0, acc1;

    auto stage2 = [&](int buf, short8 v0, short8 v1) {
        *(short8*)&At[buf][ar][ac]     = v0;
        *(short8*)&At[buf][ar][ac + 8] = v1;
    };
    auto mfma_chunk = [&](int buf, int k0) {
        #pragma unroll
        for (int ks = 0; ks < 4; ++ks) {
            short8 bfrag = *(const short8*)(wrow + k0 + ks * 32 + q * 8);
            short8 a0 = *(const short8*)&At[buf][n][ks * 32 + q * 8];
            short8 a1 = *(const short8*)&At[buf][16 + n][ks * 32 + q * 8];
            acc0 = __builtin_amdgcn_mfma_f32_16x16x32_bf16(a0, bfrag, acc0, 0, 0, 0);
            acc1 = __builtin_amdgcn_mfma_f32_16x16x32_bf16(a1, bfrag, acc1, 0, 0, 0);
        }
    };

    // x-part of step t's gates (K columns 1024..1535), no h dependency
    auto compute_x = [&](int t) {
        acc0 = (f32x4){0.f, 0.f, 0.f, 0.f};
        acc1 = (f32x4){0.f, 0.f, 0.f, 0.f};
        const short* xp = xbase + (size_t)t * (BB * EE);
        stage2(0, *(const short8*)xp, *(const short8*)(xp + 8));
        __syncthreads();
        #pragma unroll
        for (int c = 0; c < 4; ++c) {
            short8 r0, r1;
            if (c < 3) {
                r0 = *(const short8*)(xp + (c + 1) * 128);
                r1 = *(const short8*)(xp + (c + 1) * 128 + 8);
            }
            mfma_chunk(c & 1, HH + c * 128);
            if (c < 3) { stage2((c & 1) ^ 1, r0, r1); __syncthreads(); }
        }
    };

    // h-part of step t's gates (K columns 0..1023), coherent h loads
    auto compute_h = [&](int t) {
        const short* hp = (t & 1) ? hrow1 : hrow0;
        stage2(0, load_h16(hp), load_h16(hp + 8));
        __syncthreads();
        #pragma unroll
        for (int c = 0; c < 8; ++c) {
            short8 r0, r1;
            if (c < 7) {
                r0 = load_h16(hp + (c + 1) * 128);
                r1 = load_h16(hp + (c + 1) * 128 + 8);
            }
            mfma_chunk(c & 1, c * 128);
            if (c < 7) { stage2((c & 1) ^ 1, r0, r1); __syncthreads(); }
        }
    };

    compute_x(0);
    for (int t = 0; t < TT; ++t) {
        if (t > 0) {
            // wait for h(t-1): gen reaches t when all 64 group blocks arrived
            if (tid == 0) {
                while (__hip_atomic_load(gen, __ATOMIC_RELAXED, __HIP_MEMORY_SCOPE_AGENT)
                       < (unsigned)t)
                    __builtin_amdgcn_s_sleep(2);
            }
            __syncthreads();
            compute_h(t);
        }

        // Gate exchange through LDS
        #pragma unroll
        for (int r = 0; r < 4; ++r) {
            Gt[wv][q * 4 + r][n]      = acc0[r];
            Gt[wv][16 + q * 4 + r][n] = acc1[r];
        }
        __syncthreads();

        // Elementwise cell update (c in registers); coherent packed h store
        unsigned hw;
        {
            unsigned short hlo, hhi;
            #pragma unroll
            for (int u = 0; u < 2; ++u) {
                float ip = Gt[0][m][n2 + u] + bi[u];
                float fp = Gt[1][m][n2 + u] + bf_[u];
                float gp = Gt[2][m][n2 + u] + bg[u];
                float op = Gt[3][m][n2 + u] + bo[u];
                float cn = sigf(fp) * creg[u] + sigf(ip) * tanh_fast(gp);
                creg[u]  = cn;
                unsigned short hb = (unsigned short)f2bf(sigf(op) * tanh_fast(cn));
                if (u == 0) hlo = hb; else hhi = hb;
            }
            hw = (unsigned)hlo | ((unsigned)hhi << 16);
        }
        __hip_atomic_store((t & 1) ? hout_o : hout_e, hw,
                           __ATOMIC_RELAXED, __HIP_MEMORY_SCOPE_AGENT);

        if (t + 1 < TT) {
            __syncthreads();   // all h stores drained (vmcnt) before arrival
            if (tid == 0) {
                unsigned a = __hip_atomic_fetch_add(cnt, 1u, __ATOMIC_RELAXED,
                                                    __HIP_MEMORY_SCOPE_AGENT);
                if (a == 63u) {
                    __hip_atomic_store(cnt, 0u, __ATOMIC_RELAXED,
                                       __HIP_MEMORY_SCOPE_AGENT);
                    __hip_atomic_fetch_add(gen, 1u, __ATOMIC_RELEASE,
                                           __HIP_MEMORY_SCOPE_AGENT);
                }
            }
            compute_x(t + 1);  // hide barrier resolution behind x-part GEMM
        }
    }
}

// ---------------------------------------------------------------------------
// FC head: out[b] = sigmoid(dot(h[b], fc_w) + fc_b)
// ---------------------------------------------------------------------------
__global__ __launch_bounds__(256) void fc_kernel(
    const short* __restrict__ hbuf, const float* __restrict__ fc_w,
    const float* __restrict__ fc_b, float* __restrict__ out)
{
    __shared__ float red[4];
    int b = blockIdx.x;
    int tid = threadIdx.x;
    float s = 0.f;
    for (int k = tid; k < HH; k += 256)
        s += bf2f(hbuf[(size_t)b * HH + k]) * fc_w[k];
    #pragma unroll
    for (int off = 32; off > 0; off >>= 1) s += __shfl_down(s, off);
    if ((tid & 63) == 0) red[tid >> 6] = s;
    __syncthreads();
    if (tid == 0) {
        float tot = red[0] + red[1] + red[2] + red[3] + fc_b[0];
        out[b] = 1.f / (1.f + __expf(-tot));
    }
}

// ---------------------------------------------------------------------------
// Workspace layout (bytes):
//   w_cat @ 0           : 4096*1536*2   = 12,582,912
//   bias  @ 12,582,912  : 4096*4        =     16,384
//   xbf   @ 12,599,296  : 256*256*512*2 = 67,108,864
//   hbuf0 @ 79,708,160  : 524,288
//   hbuf1 @ 80,232,448  : 524,288
//   bar   @ 80,756,736  : 2,048  (8 groups x 64 u32)
// ---------------------------------------------------------------------------
extern "C" void kernel_launch(void* const* d_in, const int* in_sizes, int n_in,
                              void* d_out, int out_size, void* d_ws, size_t ws_size,
                              hipStream_t stream) {
    const int*   text = (const int*)d_in[0];
    const float* emb  = (const float*)d_in[1];
    const float* w_ih = (const float*)d_in[2];
    const float* w_hh = (const float*)d_in[3];
    const float* b_ih = (const float*)d_in[4];
    const float* b_hh = (const float*)d_in[5];
    const float* fc_w = (const float*)d_in[6];
    const float* fc_b = (const float*)d_in[7];
    float* out = (float*)d_out;

    char* ws = (char*)d_ws;
    short* w_cat = (short*)(ws);
    float* bias  = (float*)(ws + 12582912);
    short* xbf   = (short*)(ws + 12599296);
    short* hbuf0 = (short*)(ws + 79708160);
    short* hbuf1 = (short*)(ws + 80232448);
    unsigned* bar = (unsigned*)(ws + 80756736);

    gather_kernel<<<dim3(BB * TT / 4), dim3(256), 0, stream>>>(text, emb, xbf);
    prep_kernel<<<dim3(G4), dim3(256), 0, stream>>>(w_ih, w_hh, b_ih, b_hh,
                                                    w_cat, bias, bar);

    const short* a0 = w_cat;
    const float* a1 = bias;
    const short* a2 = xbf;
    short*       a3 = hbuf0;
    short*       a4 = hbuf1;
    unsigned*    a5 = bar;
    void* args[] = { (void*)&a0, (void*)&a1, (void*)&a2,
                     (void*)&a3, (void*)&a4, (void*)&a5 };
    hipLaunchCooperativeKernel((const void*)lstm_seq, dim3(NBLK), dim3(256),
                               args, 0, stream);

    // After t=255 (odd), final h is in hbuf0
    fc_kernel<<<dim3(BB), dim3(256), 0, stream>>>(hbuf0, fc_w, fc_b, out);
}